// Round 14
// baseline (104.371 us; speedup 1.0000x reference)
//
#include <hip/hip_runtime.h>
#include <hip/hip_fp16.h>

#define DIM 256
#define NC 16
#define NG 1000
#define CH2 3125        // 1024 * 3125 = 3.2M exactly -> 1 chunk per block
#define NB2 1024        // 4 blocks per CU (LDS 39.3KB, 512 thr)
#define T2 512

typedef _Float16 f16x8 __attribute__((ext_vector_type(8)));
typedef float f32x4 __attribute__((ext_vector_type(4)));

// ---------------------------------------------------------------------------
// K1: hidden = x @ W + b via MFMA (unchanged, ~15 us, near x-read floor).
// ---------------------------------------------------------------------------
__global__ void __launch_bounds__(256) hidden_kernel(
    const float* __restrict__ x, const float* __restrict__ W,
    const float* __restrict__ b, __half* __restrict__ hidden, int N) {
    const int lane = threadIdx.x & 63;
    const int wave = (blockIdx.x * blockDim.x + threadIdx.x) >> 6;
    const int m = lane & 15;
    const int kb = lane >> 4;

    const int nTiles = (N + 15) >> 4;
    if (wave >= nTiles) return;

    f16x8 wf[8];
#pragma unroll
    for (int s = 0; s < 8; ++s) {
        const float* wp = W + (size_t)(s * 32 + kb * 8) * NC + m;
        wf[s] = (f16x8){(_Float16)wp[0 * NC], (_Float16)wp[1 * NC],
                        (_Float16)wp[2 * NC], (_Float16)wp[3 * NC],
                        (_Float16)wp[4 * NC], (_Float16)wp[5 * NC],
                        (_Float16)wp[6 * NC], (_Float16)wp[7 * NC]};
    }
    const float bias = b[m];

    const int node0 = wave * 16;
    const int row = min(node0 + m, N - 1);
    const float* xp = x + (size_t)row * DIM + kb * 8;

    float4 ra[8], rb[8];
#pragma unroll
    for (int s = 0; s < 8; ++s) {
        ra[s] = *(const float4*)(xp + s * 32);
        rb[s] = *(const float4*)(xp + s * 32 + 4);
    }

    f32x4 acc = {0.f, 0.f, 0.f, 0.f};
#pragma unroll
    for (int s = 0; s < 8; ++s) {
        f16x8 af = (f16x8){(_Float16)ra[s].x, (_Float16)ra[s].y,
                           (_Float16)ra[s].z, (_Float16)ra[s].w,
                           (_Float16)rb[s].x, (_Float16)rb[s].y,
                           (_Float16)rb[s].z, (_Float16)rb[s].w};
        acc = __builtin_amdgcn_mfma_f32_16x16x32_f16(af, wf[s], acc, 0, 0, 0);
    }

#pragma unroll
    for (int j = 0; j < 4; ++j) {
        int node = node0 + kb * 4 + j;
        if (node < N)
            hidden[(size_t)node * NC + m] = __float2half(acc[j] + bias);
    }
}

// ---------------------------------------------------------------------------
// K2: node -> graph id as u16 (searchsorted 'right'; 200KB table, L1-friendly)
// ---------------------------------------------------------------------------
__global__ void seg_kernel(const int* __restrict__ ed_idx,
                           unsigned short* __restrict__ node_seg, int N, int G) {
    int n = blockIdx.x * blockDim.x + threadIdx.x;
    if (n >= N) return;
    int lo = 0, hi = G;
    while (lo < hi) {
        int mid = (lo + hi) >> 1;
        if (ed_idx[mid] <= n) lo = mid + 1; else hi = mid;
    }
    node_seg[n] = (unsigned short)lo;
}

// ---------------------------------------------------------------------------
// K3: fused sort+pool, restructured for PHASE DIVERSITY: 512 threads,
// CHUNK=3125, 1024 blocks -> 4 independent blocks per CU in different phases
// (gather latency of one overlaps atomics/VALU of another). LDS 39.3KB:
// basearr eliminated (pool derives run start = cursor[g] - hist[g] after
// pass B). Hot-graph pool tail halved (max run ~22). Round-11 two-atomic-
// pass structure retained (no cross-barrier register liveness).
// ---------------------------------------------------------------------------
__global__ void __launch_bounds__(T2, 8) gcn_pool_kernel(
    const int* __restrict__ rows, const int* __restrict__ cols,
    const float* __restrict__ vals, const __half* __restrict__ hidden,
    const unsigned short* __restrict__ node_seg,
    float* __restrict__ partials, int nE) {
    __shared__ unsigned hist[NG];
    __shared__ unsigned cursor[NG];
    __shared__ unsigned wsum[T2 / 64];
    __shared__ unsigned short raw_g[CH2];
    __shared__ uint2 sorted[CH2];

    const int t = threadIdx.x, lane = t & 63, wid = t >> 6;
    const int beg = blockIdx.x * CH2;
    const int cnt = min(nE - beg, CH2);

    for (int i = t; i < NG; i += T2) hist[i] = 0u;
    __syncthreads();

    // ---- pass A: rows stream + u16 seg gather + hist atomic ----
    for (int i = t; i < cnt; i += 2 * T2) {
        int i2 = i + T2;
        bool ok2 = i2 < cnt;
        int r1 = rows[beg + i];
        int r2 = rows[beg + (ok2 ? i2 : i)];
        unsigned g1 = node_seg[r1];
        unsigned g2 = node_seg[r2];
        raw_g[i] = (unsigned short)g1;
        if (g1 < NG) atomicAdd(&hist[g1], 1u);
        if (ok2) {
            raw_g[i2] = (unsigned short)g2;
            if (g2 < NG) atomicAdd(&hist[g2], 1u);
        }
    }
    __syncthreads();

    // ---- pair scan: thread t<500 owns bins (2t, 2t+1) ----
    unsigned h0 = 0, s = 0;
    if (t < 500) { h0 = hist[2 * t]; s = h0 + hist[2 * t + 1]; }
    unsigned inc = s;
#pragma unroll
    for (int d = 1; d < 64; d <<= 1) {
        unsigned u = __shfl_up(inc, d);
        if (lane >= d) inc += u;
    }
    if (lane == 63) wsum[wid] = inc;
    __syncthreads();
    if (wid == 0) {
        unsigned v2 = (lane < T2 / 64) ? wsum[lane] : 0u;
        unsigned inc2 = v2;
#pragma unroll
        for (int d = 1; d < T2 / 64; d <<= 1) {
            unsigned u = __shfl_up(inc2, d);
            if (lane >= d) inc2 += u;
        }
        if (lane < T2 / 64) wsum[lane] = inc2 - v2;   // exclusive wave base
    }
    __syncthreads();
    unsigned ex = wsum[wid] + inc - s;                // exclusive pair base
    if (t < 500) {
        cursor[2 * t]     = ex;
        cursor[2 * t + 1] = ex + h0;
    }
    __syncthreads();

    // ---- pass B: cols/vals stream (first read) + LDS scatter ----
    for (int i = t; i < cnt; i += T2) {
        unsigned g = raw_g[i];
        if (g < NG) {
            unsigned pos = atomicAdd(&cursor[g], 1u);
            sorted[pos] = make_uint2((unsigned)cols[beg + i],
                                     __float_as_uint(vals[beg + i]));
        }
    }
    __syncthreads();

    // ---- pool: thread t owns graphs t and t+512; run = [cur-h, cur) ----
    float4* pbase = (float4*)(partials + (size_t)blockIdx.x * (NG * NC));
#pragma unroll
    for (int half = 0; half < 2; ++half) {
        int g = t + half * T2;
        if (g >= NG) break;
        float acc[NC];
#pragma unroll
        for (int c = 0; c < NC; ++c) acc[c] = 0.f;

        unsigned cg = hist[g];
        if (cg) {
            unsigned i = cursor[g] - cg, end = cursor[g];
            uint2 cve = sorted[i];
            uint4 h0v = *(const uint4*)(hidden + (size_t)cve.x * NC);
            uint4 h1v = *(const uint4*)(hidden + (size_t)cve.x * NC + 8);
            while (i < end) {
                unsigned nx = i + 1;
                uint2 cvn = cve;
                uint4 h0n = h0v, h1n = h1v;
                if (nx < end) {                 // prefetch next edge
                    cvn = sorted[nx];
                    h0n = *(const uint4*)(hidden + (size_t)cvn.x * NC);
                    h1n = *(const uint4*)(hidden + (size_t)cvn.x * NC + 8);
                }
                float vv = __uint_as_float(cve.y);
                const __half2* q0 = (const __half2*)&h0v;
                const __half2* q1 = (const __half2*)&h1v;
#pragma unroll
                for (int k = 0; k < 4; ++k) {
                    float2 f0 = __half22float2(q0[k]);
                    float2 f1 = __half22float2(q1[k]);
                    acc[2 * k]         = fmaf(vv, f0.x, acc[2 * k]);
                    acc[2 * k + 1]     = fmaf(vv, f0.y, acc[2 * k + 1]);
                    acc[8 + 2 * k]     = fmaf(vv, f1.x, acc[8 + 2 * k]);
                    acc[8 + 2 * k + 1] = fmaf(vv, f1.y, acc[8 + 2 * k + 1]);
                }
                cve = cvn; h0v = h0n; h1v = h1n; i = nx;
            }
        }
        float4* p = pbase + (size_t)g * (NC / 4);
        p[0] = make_float4(acc[0], acc[1], acc[2], acc[3]);
        p[1] = make_float4(acc[4], acc[5], acc[6], acc[7]);
        p[2] = make_float4(acc[8], acc[9], acc[10], acc[11]);
        p[3] = make_float4(acc[12], acc[13], acc[14], acc[15]);
    }
}

// ---------------------------------------------------------------------------
// K4: fold partials[NB2][NG*NC] into out; blockIdx.y picks 128 slices.
// ---------------------------------------------------------------------------
__global__ void reduce_kernel(const float* __restrict__ partials,
                              float* __restrict__ out) {
    int i = blockIdx.x * blockDim.x + threadIdx.x;
    if (i >= NG * NC) return;
    const int per = NB2 / 8;  // 128
    const float* p = partials + (size_t)(blockIdx.y * per) * (NG * NC) + i;
    float s0 = 0.f, s1 = 0.f, s2 = 0.f, s3 = 0.f;
#pragma unroll 4
    for (int k = 0; k < per; k += 4) {
        s0 += p[(size_t)(k + 0) * (NG * NC)];
        s1 += p[(size_t)(k + 1) * (NG * NC)];
        s2 += p[(size_t)(k + 2) * (NG * NC)];
        s3 += p[(size_t)(k + 3) * (NG * NC)];
    }
    atomicAdd(&out[i], (s0 + s1) + (s2 + s3));
}

extern "C" void kernel_launch(void* const* d_in, const int* in_sizes, int n_in,
                              void* d_out, int out_size, void* d_ws, size_t ws_size,
                              hipStream_t stream) {
    const float* x      = (const float*)d_in[0];
    const int*   ed_idx = (const int*)  d_in[1];
    const int*   rows   = (const int*)  d_in[2];
    const int*   cols   = (const int*)  d_in[3];
    const float* vals   = (const float*)d_in[4];
    const float* W      = (const float*)d_in[5];
    const float* b      = (const float*)d_in[6];
    float* out = (float*)d_out;

    int N  = in_sizes[0] / DIM;   // 100000
    int G  = in_sizes[1];         // 1000
    int nE = in_sizes[2];         // 3200000

    size_t off = 0;
    auto alloc = [&](size_t bytes, size_t align) {
        off = (off + align - 1) / align * align;
        size_t r = off; off += bytes; return r;
    };
    __half* hidden = (__half*)((char*)d_ws + alloc((size_t)N * NC * 2, 16));
    unsigned short* node_seg =
        (unsigned short*)((char*)d_ws + alloc((size_t)N * 2, 16));
    float* partials =
        (float*)((char*)d_ws + alloc((size_t)NB2 * NG * NC * 4, 16));
    (void)ws_size;

    (void)hipMemsetAsync(d_out, 0, (size_t)out_size * sizeof(float), stream);

    seg_kernel<<<(N + 255) / 256, 256, 0, stream>>>(ed_idx, node_seg, N, G);
    int nTiles = (N + 15) / 16;
    int hblocks = (nTiles + 3) / 4;
    hidden_kernel<<<hblocks, 256, 0, stream>>>(x, W, b, hidden, N);
    gcn_pool_kernel<<<NB2, T2, 0, stream>>>(rows, cols, vals, hidden,
                                            node_seg, partials, nE);
    dim3 rg((NG * NC + 255) / 256, 8);
    reduce_kernel<<<rg, 256, 0, stream>>>(partials, out);
}